// Round 1
// baseline (9987.516 us; speedup 1.0000x reference)
//
#include <hip/hip_runtime.h>

#define N_NODES 100000
#define N_EDGES 1600000
#define D_FEAT 48
#define K_ITER 10

// ---------------------------------------------------------------------------
// deg[row[e]] += w[e]
__global__ void k_deg(const int* __restrict__ row, const float* __restrict__ w,
                      float* __restrict__ deg, int E) {
    int i = blockIdx.x * blockDim.x + threadIdx.x;
    if (i < E) atomicAdd(&deg[row[i]], w[i]);
}

// norm[e] = 0.9 * w[e] / (deg[row[e]] + 1e-10)   (fold (1-ALPHA) into norm)
__global__ void k_norm(const int* __restrict__ row, const float* __restrict__ w,
                       const float* __restrict__ deg, float* __restrict__ norm, int E) {
    int i = blockIdx.x * blockDim.x + threadIdx.x;
    if (i < E) norm[i] = 0.9f * w[i] / (deg[row[i]] + 1e-10f);
}

// dst = 0.1 * x   (vectorized float4; N_NODES*12 float4 elements)
__global__ void k_init(const float4* __restrict__ x, float4* __restrict__ dst, int n4) {
    int i = blockIdx.x * blockDim.x + threadIdx.x;
    if (i < n4) {
        float4 v = x[i];
        dst[i] = make_float4(0.1f * v.x, 0.1f * v.y, 0.1f * v.z, 0.1f * v.w);
    }
}

// One thread per (edge, 4-feature chunk): 12 consecutive threads share an edge.
// dst[row[e]*48 + c*4 .. +3] += norm[e] * h[col[e]*48 + c*4 .. +3]
__global__ void k_scatter(const int* __restrict__ row, const int* __restrict__ col,
                          const float* __restrict__ norm,
                          const float4* __restrict__ h, float* __restrict__ dst, int E) {
    int idx = blockIdx.x * blockDim.x + threadIdx.x;   // < E*12 = 19.2M, fits int32
    if (idx >= E * 12) return;
    int e = idx / 12;
    int c = idx - e * 12;
    float nv = norm[e];
    float4 hv = h[col[e] * 12 + c];
    float* d = dst + row[e] * 48 + c * 4;
    atomicAdd(d + 0, nv * hv.x);
    atomicAdd(d + 1, nv * hv.y);
    atomicAdd(d + 2, nv * hv.z);
    atomicAdd(d + 3, nv * hv.w);
}

extern "C" void kernel_launch(void* const* d_in, const int* in_sizes, int n_in,
                              void* d_out, int out_size, void* d_ws, size_t ws_size,
                              hipStream_t stream) {
    const float* x  = (const float*)d_in[0];
    const int*   ei = (const int*)d_in[1];
    const float* w  = (const float*)d_in[2];
    const int E = in_sizes[2];              // 1,600,000
    const int* row = ei;                    // edge_index[0] = destination (segment id)
    const int* col = ei + E;                // edge_index[1] = source of message

    // Workspace layout (all 16B-aligned):
    //   deg  : N_NODES floats            @ 0          (400,000 B)
    //   norm : E floats                  @ 400,000    (6,400,000 B)
    //   hA   : N_NODES*48 floats         @ 6,800,000  (19,200,000 B)
    char* ws = (char*)d_ws;
    float* deg  = (float*)(ws);
    float* norm = (float*)(ws + 400000);
    float* hA   = (float*)(ws + 6800000);
    float* out  = (float*)d_out;

    const int B = 256;

    hipMemsetAsync(deg, 0, N_NODES * sizeof(float), stream);
    k_deg <<<(E + B - 1) / B, B, 0, stream>>>(row, w, deg, E);
    k_norm<<<(E + B - 1) / B, B, 0, stream>>>(row, w, deg, norm, E);

    const int n4 = N_NODES * 12;       // float4 count of an h buffer
    const int nscat = E * 12;          // scatter threads

    const float* src = x;
    for (int k = 1; k <= K_ITER; ++k) {
        float* dst = (k & 1) ? hA : out;   // K even -> final iteration writes d_out
        k_init<<<(n4 + B - 1) / B, B, 0, stream>>>((const float4*)x, (float4*)dst, n4);
        k_scatter<<<(nscat + B - 1) / B, B, 0, stream>>>(row, col, norm,
                                                         (const float4*)src, dst, E);
        src = dst;
    }
}

// Round 2
// 1145.498 us; speedup vs baseline: 8.7189x; 8.7189x over previous
//
#include <hip/hip_runtime.h>

#define N_NODES 100000
#define N_EDGES 1600000
#define D_FEAT 48
#define K_ITER 10

#define SCAN_THREADS 1024
#define TPN 12   // threads per node (one float4 chunk each)
#define NPB 16   // nodes per block (block = 192 threads)

// cnt[row[e]]++ ; deg[row[e]] += w[e]
__global__ void k_count(const int* __restrict__ row, const float* __restrict__ w,
                        int* __restrict__ cnt, float* __restrict__ deg, int E) {
    int i = blockIdx.x * blockDim.x + threadIdx.x;
    if (i < E) {
        int r = row[i];
        atomicAdd(&cnt[r], 1);
        atomicAdd(&deg[r], w[i]);
    }
}

// Single-workgroup exclusive scan: rowptr[0..n] from cnt[0..n-1].
__global__ void k_scan(const int* __restrict__ cnt, int* __restrict__ rowptr, int n) {
    __shared__ int sums[SCAN_THREADS];
    int t = threadIdx.x;
    int chunk = (n + SCAN_THREADS - 1) / SCAN_THREADS;
    int lo = t * chunk;
    int hi = lo + chunk; if (hi > n) hi = n; if (lo > n) lo = n;
    int s = 0;
    for (int i = lo; i < hi; ++i) s += cnt[i];
    sums[t] = s;
    __syncthreads();
    for (int off = 1; off < SCAN_THREADS; off <<= 1) {
        int v = 0;
        if (t >= off) v = sums[t - off];
        __syncthreads();
        sums[t] += v;
        __syncthreads();
    }
    int run = (t == 0) ? 0 : sums[t - 1];
    for (int i = lo; i < hi; ++i) {
        rowptr[i] = run;
        run += cnt[i];
    }
    if (t == SCAN_THREADS - 1) rowptr[n] = run;
}

// Bucket-fill CSR: ccol[pos] = col[e]; cnorm[pos] = 0.9*w/(deg[row]+1e-10)
__global__ void k_fill(const int* __restrict__ row, const int* __restrict__ col,
                       const float* __restrict__ w, const float* __restrict__ deg,
                       const int* __restrict__ rowptr, int* __restrict__ cursor,
                       int* __restrict__ ccol, float* __restrict__ cnorm, int E) {
    int i = blockIdx.x * blockDim.x + threadIdx.x;
    if (i < E) {
        int r = row[i];
        int pos = rowptr[r] + atomicAdd(&cursor[r], 1);
        ccol[pos] = col[i];
        cnorm[pos] = 0.9f * w[i] / (deg[r] + 1e-10f);
    }
}

// Pull-based propagation: dst[n] = 0.1*x[n] + sum_e norm[e]*h[ccol[e]]
// 12 threads per node; thread c owns float4 chunk c of the 48-float feature.
__global__ void k_pull(const int* __restrict__ rowptr, const int* __restrict__ ccol,
                       const float* __restrict__ cnorm,
                       const float4* __restrict__ h, const float4* __restrict__ x,
                       float4* __restrict__ dst) {
    int node = blockIdx.x * NPB + threadIdx.x / TPN;
    int c = threadIdx.x % TPN;
    if (node >= N_NODES) return;
    int beg = rowptr[node], end = rowptr[node + 1];
    float4 acc = make_float4(0.f, 0.f, 0.f, 0.f);
    for (int e = beg; e < end; ++e) {
        float nv = cnorm[e];          // broadcast across the 12 lanes
        float4 hv = h[ccol[e] * TPN + c];
        acc.x += nv * hv.x; acc.y += nv * hv.y;
        acc.z += nv * hv.z; acc.w += nv * hv.w;
    }
    float4 xv = x[node * TPN + c];
    dst[node * TPN + c] = make_float4(acc.x + 0.1f * xv.x, acc.y + 0.1f * xv.y,
                                      acc.z + 0.1f * xv.z, acc.w + 0.1f * xv.w);
}

extern "C" void kernel_launch(void* const* d_in, const int* in_sizes, int n_in,
                              void* d_out, int out_size, void* d_ws, size_t ws_size,
                              hipStream_t stream) {
    const float* x  = (const float*)d_in[0];
    const int*   ei = (const int*)d_in[1];
    const float* w  = (const float*)d_in[2];
    const int E = in_sizes[2];
    const int* row = ei;        // destination (segment id)
    const int* col = ei + E;    // message source

    // Workspace layout (16B aligned):
    //   cnt/cursor : int[N]      @ 0           (400,000 B)
    //   deg        : float[N]    @ 400,000     (400,000 B)
    //   rowptr     : int[N+1]    @ 800,000     (400,004 B -> pad to 1,200,016)
    //   ccol       : int[E]      @ 1,200,016   (6,400,000 B)
    //   cnorm      : float[E]    @ 7,600,016   (6,400,000 B)
    //   hA         : float[N*48] @ 14,000,016  (19,200,000 B)   total ~33.2 MB
    char* ws = (char*)d_ws;
    int*   cnt    = (int*)(ws);
    float* deg    = (float*)(ws + 400000);
    int*   rowptr = (int*)(ws + 800000);
    int*   ccol   = (int*)(ws + 1200016);
    float* cnorm  = (float*)(ws + 7600016);
    float* hA     = (float*)(ws + 14000016);
    float* out    = (float*)d_out;

    const int B = 256;
    const int egrid = (E + B - 1) / B;

    hipMemsetAsync(cnt, 0, N_NODES * sizeof(int), stream);
    hipMemsetAsync(deg, 0, N_NODES * sizeof(float), stream);
    k_count<<<egrid, B, 0, stream>>>(row, w, cnt, deg, E);
    k_scan<<<1, SCAN_THREADS, 0, stream>>>(cnt, rowptr, N_NODES);
    hipMemsetAsync(cnt, 0, N_NODES * sizeof(int), stream);   // reuse as cursor
    k_fill<<<egrid, B, 0, stream>>>(row, col, w, deg, rowptr, cnt, ccol, cnorm, E);

    const int pgrid = (N_NODES + NPB - 1) / NPB;
    const float* src = x;
    for (int k = 1; k <= K_ITER; ++k) {
        float* dst = (k & 1) ? hA : out;   // K even: final iter writes d_out
        k_pull<<<pgrid, NPB * TPN, 0, stream>>>(rowptr, ccol, cnorm,
                                                (const float4*)src, (const float4*)x,
                                                (float4*)dst);
        src = dst;
    }
}

// Round 3
// 923.146 us; speedup vs baseline: 10.8190x; 1.2409x over previous
//
#include <hip/hip_runtime.h>

#define N_NODES 100000
#define N_EDGES 1600000
#define D_FEAT 48
#define K_ITER 10

#define TPN 12   // threads per node (one float4 chunk each)
#define NPB 16   // nodes per block (block = 192 threads = 3 waves)

// scan partition: 256 threads/block, 8 elems/thread -> 2048 elems/block
#define SCAN_TB   256
#define SCAN_EPT  8
#define SCAN_SEG  (SCAN_TB * SCAN_EPT)
#define SCAN_NB   ((N_NODES + SCAN_SEG - 1) / SCAN_SEG)   // 49

// ---------------------------------------------------------------------------
// cnt[row[e]]++ ; deg[row[e]] += w[e]
__global__ void k_count(const int* __restrict__ row, const float* __restrict__ w,
                        int* __restrict__ cnt, float* __restrict__ deg, int E) {
    int i = blockIdx.x * blockDim.x + threadIdx.x;
    if (i < E) {
        int r = row[i];
        atomicAdd(&cnt[r], 1);
        atomicAdd(&deg[r], w[i]);
    }
}

// Phase A: per-thread sum of 8 elems, intra-block scan -> thread_off, blocksum
__global__ void k_scanA(const int* __restrict__ cnt, int* __restrict__ thread_off,
                        int* __restrict__ blocksum) {
    __shared__ int sh[SCAN_TB];
    int b = blockIdx.x, t = threadIdx.x;
    int base = b * SCAN_SEG + t * SCAN_EPT;
    int s = 0;
#pragma unroll
    for (int j = 0; j < SCAN_EPT; ++j) {
        int i = base + j;
        if (i < N_NODES) s += cnt[i];
    }
    sh[t] = s;
    __syncthreads();
    // Hillis-Steele inclusive scan over 256
    for (int off = 1; off < SCAN_TB; off <<= 1) {
        int v = (t >= off) ? sh[t - off] : 0;
        __syncthreads();
        sh[t] += v;
        __syncthreads();
    }
    thread_off[b * SCAN_TB + t] = sh[t] - s;   // exclusive
    if (t == SCAN_TB - 1) blocksum[b] = sh[t];
}

// Phase B: serial scan of SCAN_NB block sums (tiny), also writes rowptr[N]
__global__ void k_scanB(const int* __restrict__ blocksum, int* __restrict__ blockoff,
                        int* __restrict__ rowptr) {
    if (threadIdx.x == 0) {
        int run = 0;
        for (int b = 0; b < SCAN_NB; ++b) {
            blockoff[b] = run;
            run += blocksum[b];
        }
        rowptr[N_NODES] = run;
    }
}

// Phase C: write rowptr[i] = blockoff[b] + thread_off + running local sum
__global__ void k_scanC(const int* __restrict__ cnt, const int* __restrict__ thread_off,
                        const int* __restrict__ blockoff, int* __restrict__ rowptr) {
    int b = blockIdx.x, t = threadIdx.x;
    int base = b * SCAN_SEG + t * SCAN_EPT;
    int run = blockoff[b] + thread_off[b * SCAN_TB + t];
#pragma unroll
    for (int j = 0; j < SCAN_EPT; ++j) {
        int i = base + j;
        if (i < N_NODES) {
            rowptr[i] = run;
            run += cnt[i];
        }
    }
}

// Bucket-fill CSR: epack[pos] = { col*TPN, bits(0.9*w/(deg+1e-10)) }
__global__ void k_fill(const int* __restrict__ row, const int* __restrict__ col,
                       const float* __restrict__ w, const float* __restrict__ deg,
                       const int* __restrict__ rowptr, int* __restrict__ cursor,
                       int2* __restrict__ epack, int E) {
    int i = blockIdx.x * blockDim.x + threadIdx.x;
    if (i < E) {
        int r = row[i];
        int pos = rowptr[r] + atomicAdd(&cursor[r], 1);
        float nv = 0.9f * w[i] / (deg[r] + 1e-10f);
        epack[pos] = make_int2(col[i] * TPN, __float_as_int(nv));
    }
}

// Pull: dst[n] = 0.1*x[n] + sum_e norm[e]*h[col[e]]
// 12 threads/node, 4-deep unrolled edge loop for memory-level parallelism.
__global__ void k_pull(const int* __restrict__ rowptr, const int2* __restrict__ epack,
                       const float4* __restrict__ h, const float4* __restrict__ x,
                       float4* __restrict__ dst) {
    int node = blockIdx.x * NPB + threadIdx.x / TPN;
    int c = threadIdx.x % TPN;
    if (node >= N_NODES) return;
    int beg = rowptr[node], end = rowptr[node + 1];
    float4 xv = x[node * TPN + c];
    float4 a0 = make_float4(0.1f * xv.x, 0.1f * xv.y, 0.1f * xv.z, 0.1f * xv.w);
    float4 a1 = make_float4(0.f, 0.f, 0.f, 0.f);
    float4 a2 = make_float4(0.f, 0.f, 0.f, 0.f);
    float4 a3 = make_float4(0.f, 0.f, 0.f, 0.f);
    int e = beg;
    for (; e + 4 <= end; e += 4) {
        int2 p0 = epack[e + 0], p1 = epack[e + 1], p2 = epack[e + 2], p3 = epack[e + 3];
        float4 h0 = h[p0.x + c];
        float4 h1 = h[p1.x + c];
        float4 h2 = h[p2.x + c];
        float4 h3 = h[p3.x + c];
        float n0 = __int_as_float(p0.y), n1 = __int_as_float(p1.y);
        float n2 = __int_as_float(p2.y), n3 = __int_as_float(p3.y);
        a0.x += n0 * h0.x; a0.y += n0 * h0.y; a0.z += n0 * h0.z; a0.w += n0 * h0.w;
        a1.x += n1 * h1.x; a1.y += n1 * h1.y; a1.z += n1 * h1.z; a1.w += n1 * h1.w;
        a2.x += n2 * h2.x; a2.y += n2 * h2.y; a2.z += n2 * h2.z; a2.w += n2 * h2.w;
        a3.x += n3 * h3.x; a3.y += n3 * h3.y; a3.z += n3 * h3.z; a3.w += n3 * h3.w;
    }
    for (; e < end; ++e) {
        int2 p = epack[e];
        float4 hv = h[p.x + c];
        float nv = __int_as_float(p.y);
        a0.x += nv * hv.x; a0.y += nv * hv.y; a0.z += nv * hv.z; a0.w += nv * hv.w;
    }
    float4 acc = make_float4(a0.x + a1.x + a2.x + a3.x,
                             a0.y + a1.y + a2.y + a3.y,
                             a0.z + a1.z + a2.z + a3.z,
                             a0.w + a1.w + a2.w + a3.w);
    dst[node * TPN + c] = acc;
}

extern "C" void kernel_launch(void* const* d_in, const int* in_sizes, int n_in,
                              void* d_out, int out_size, void* d_ws, size_t ws_size,
                              hipStream_t stream) {
    const float* x  = (const float*)d_in[0];
    const int*   ei = (const int*)d_in[1];
    const float* w  = (const float*)d_in[2];
    const int E = in_sizes[2];
    const int* row = ei;        // destination (segment id)
    const int* col = ei + E;    // message source

    // Workspace layout (16B aligned), total ~33.2 MB (same footprint as R2):
    //   cnt/cursor : int[N]      @ 0
    //   deg        : float[N]    @ 400,000
    //   rowptr     : int[N+1]    @ 800,000
    //   epack      : int2[E]     @ 1,200,016   (12,800,000 B)
    //   hA         : float[N*48] @ 14,000,016  (19,200,000 B)
    // Scan temporaries overlap hA (dead until first k_pull):
    //   thread_off : int[49*256] @ 14,000,016
    //   blocksum   : int[49]     @ 14,050,192
    //   blockoff   : int[49]     @ 14,050,448
    char* ws = (char*)d_ws;
    int*   cnt        = (int*)(ws);
    float* deg        = (float*)(ws + 400000);
    int*   rowptr     = (int*)(ws + 800000);
    int2*  epack      = (int2*)(ws + 1200016);
    float* hA         = (float*)(ws + 14000016);
    int*   thread_off = (int*)(ws + 14000016);
    int*   blocksum   = (int*)(ws + 14050192);
    int*   blockoff   = (int*)(ws + 14050448);
    float* out        = (float*)d_out;

    const int B = 256;
    const int egrid = (E + B - 1) / B;

    hipMemsetAsync(cnt, 0, N_NODES * sizeof(int), stream);
    hipMemsetAsync(deg, 0, N_NODES * sizeof(float), stream);
    k_count<<<egrid, B, 0, stream>>>(row, w, cnt, deg, E);
    k_scanA<<<SCAN_NB, SCAN_TB, 0, stream>>>(cnt, thread_off, blocksum);
    k_scanB<<<1, 64, 0, stream>>>(blocksum, blockoff, rowptr);
    k_scanC<<<SCAN_NB, SCAN_TB, 0, stream>>>(cnt, thread_off, blockoff, rowptr);
    hipMemsetAsync(cnt, 0, N_NODES * sizeof(int), stream);   // reuse as cursor
    k_fill<<<egrid, B, 0, stream>>>(row, col, w, deg, rowptr, cnt, epack, E);

    const int pgrid = (N_NODES + NPB - 1) / NPB;
    const float* src = x;
    for (int k = 1; k <= K_ITER; ++k) {
        float* dst = (k & 1) ? hA : out;   // K even: final iter writes d_out
        k_pull<<<pgrid, NPB * TPN, 0, stream>>>(rowptr, epack,
                                                (const float4*)src, (const float4*)x,
                                                (float4*)dst);
        src = dst;
    }
}

// Round 4
// 631.055 us; speedup vs baseline: 15.8267x; 1.4629x over previous
//
#include <hip/hip_runtime.h>
#include <hip/hip_fp16.h>

#define N_NODES 100000
#define N_EDGES 1600000
#define D_FEAT 48
#define K_ITER 10

#define TPN 12   // threads per node (4 features each)
#define NPB 16   // nodes per block (block = 192 threads = 3 waves)

// scan partition: 256 threads/block, 8 elems/thread -> 2048 elems/block
#define SCAN_TB   256
#define SCAN_EPT  8
#define SCAN_SEG  (SCAN_TB * SCAN_EPT)
#define SCAN_NB   ((N_NODES + SCAN_SEG - 1) / SCAN_SEG)   // 49

// ---------------------------------------------------------------------------
// pos_local[e] = cnt[row[e]]++   (only int atomics; deg handled later w/o atomics)
__global__ void k_count(const int* __restrict__ row, int* __restrict__ cnt,
                        int* __restrict__ pos_local, int E) {
    int i = blockIdx.x * blockDim.x + threadIdx.x;
    if (i < E) pos_local[i] = atomicAdd(&cnt[row[i]], 1);
}

__global__ void k_scanA(const int* __restrict__ cnt, int* __restrict__ thread_off,
                        int* __restrict__ blocksum) {
    __shared__ int sh[SCAN_TB];
    int b = blockIdx.x, t = threadIdx.x;
    int base = b * SCAN_SEG + t * SCAN_EPT;
    int s = 0;
#pragma unroll
    for (int j = 0; j < SCAN_EPT; ++j) {
        int i = base + j;
        if (i < N_NODES) s += cnt[i];
    }
    sh[t] = s;
    __syncthreads();
    for (int off = 1; off < SCAN_TB; off <<= 1) {
        int v = (t >= off) ? sh[t - off] : 0;
        __syncthreads();
        sh[t] += v;
        __syncthreads();
    }
    thread_off[b * SCAN_TB + t] = sh[t] - s;   // exclusive
    if (t == SCAN_TB - 1) blocksum[b] = sh[t];
}

__global__ void k_scanB(const int* __restrict__ blocksum, int* __restrict__ blockoff,
                        int* __restrict__ rowptr) {
    if (threadIdx.x == 0) {
        int run = 0;
        for (int b = 0; b < SCAN_NB; ++b) {
            blockoff[b] = run;
            run += blocksum[b];
        }
        rowptr[N_NODES] = run;
    }
}

__global__ void k_scanC(const int* __restrict__ cnt, const int* __restrict__ thread_off,
                        const int* __restrict__ blockoff, int* __restrict__ rowptr) {
    int b = blockIdx.x, t = threadIdx.x;
    int base = b * SCAN_SEG + t * SCAN_EPT;
    int run = blockoff[b] + thread_off[b * SCAN_TB + t];
#pragma unroll
    for (int j = 0; j < SCAN_EPT; ++j) {
        int i = base + j;
        if (i < N_NODES) {
            rowptr[i] = run;
            run += cnt[i];
        }
    }
}

// Atomic-free fill: epack[rowptr[r]+pos_local[e]] = { col*TPN, bits(w) }
__global__ void k_fill(const int* __restrict__ row, const int* __restrict__ col,
                       const float* __restrict__ w, const int* __restrict__ rowptr,
                       const int* __restrict__ pos_local, int2* __restrict__ epack, int E) {
    int i = blockIdx.x * blockDim.x + threadIdx.x;
    if (i < E) {
        int pos = rowptr[row[i]] + pos_local[i];
        epack[pos] = make_int2(col[i] * TPN, __float_as_int(w[i]));
    }
}

// Segmented deg sum + in-place norm rescale: epack.y = 0.9*w/(deg+1e-10)
__global__ void k_norm(const int* __restrict__ rowptr, int2* __restrict__ epack) {
    int n = blockIdx.x * blockDim.x + threadIdx.x;
    if (n >= N_NODES) return;
    int beg = rowptr[n], end = rowptr[n + 1];
    float s = 0.f;
    for (int e = beg; e < end; ++e) s += __int_as_float(epack[e].y);
    float scale = 0.9f / (s + 1e-10f);
    for (int e = beg; e < end; ++e)
        epack[e].y = __float_as_int(__int_as_float(epack[e].y) * scale);
}

// Convert x (fp32) -> fp16 buffer (N*48 halves), 4 floats per thread
__global__ void k_x2h(const float4* __restrict__ x, float2* __restrict__ dst, int n) {
    int i = blockIdx.x * blockDim.x + threadIdx.x;
    if (i < n) {
        float4 v = x[i];
        __half2 a = __floats2half2_rn(v.x, v.y);
        __half2 b = __floats2half2_rn(v.z, v.w);
        float2 o;
        *(__half2*)&o.x = a;
        *(__half2*)&o.y = b;
        dst[i] = o;
    }
}

// Pull iteration, fp16 gather -> fp16 store.
// Thread c of a node loads 4 halves (8B) at src16[col*12 + c].
__global__ void k_pull16(const int* __restrict__ rowptr, const int2* __restrict__ epack,
                         const float2* __restrict__ src16, const float4* __restrict__ x,
                         float2* __restrict__ dst16) {
    int node = blockIdx.x * NPB + threadIdx.x / TPN;
    int c = threadIdx.x % TPN;
    if (node >= N_NODES) return;
    int beg = rowptr[node], end = rowptr[node + 1];
    float4 xv = x[node * TPN + c];
    float4 a0 = make_float4(0.1f * xv.x, 0.1f * xv.y, 0.1f * xv.z, 0.1f * xv.w);
    float4 a1 = make_float4(0.f, 0.f, 0.f, 0.f);
    float4 a2 = make_float4(0.f, 0.f, 0.f, 0.f);
    float4 a3 = make_float4(0.f, 0.f, 0.f, 0.f);
    int e = beg;
    for (; e + 4 <= end; e += 4) {
        int2 p0 = epack[e], p1 = epack[e + 1], p2 = epack[e + 2], p3 = epack[e + 3];
        float2 r0 = src16[p0.x + c];
        float2 r1 = src16[p1.x + c];
        float2 r2 = src16[p2.x + c];
        float2 r3 = src16[p3.x + c];
        float n0 = __int_as_float(p0.y), n1 = __int_as_float(p1.y);
        float n2 = __int_as_float(p2.y), n3 = __int_as_float(p3.y);
        float2 f0a = __half22float2(*(__half2*)&r0.x), f0b = __half22float2(*(__half2*)&r0.y);
        float2 f1a = __half22float2(*(__half2*)&r1.x), f1b = __half22float2(*(__half2*)&r1.y);
        float2 f2a = __half22float2(*(__half2*)&r2.x), f2b = __half22float2(*(__half2*)&r2.y);
        float2 f3a = __half22float2(*(__half2*)&r3.x), f3b = __half22float2(*(__half2*)&r3.y);
        a0.x += n0 * f0a.x; a0.y += n0 * f0a.y; a0.z += n0 * f0b.x; a0.w += n0 * f0b.y;
        a1.x += n1 * f1a.x; a1.y += n1 * f1a.y; a1.z += n1 * f1b.x; a1.w += n1 * f1b.y;
        a2.x += n2 * f2a.x; a2.y += n2 * f2a.y; a2.z += n2 * f2b.x; a2.w += n2 * f2b.y;
        a3.x += n3 * f3a.x; a3.y += n3 * f3a.y; a3.z += n3 * f3b.x; a3.w += n3 * f3b.y;
    }
    for (; e < end; ++e) {
        int2 p = epack[e];
        float2 r = src16[p.x + c];
        float nv = __int_as_float(p.y);
        float2 fa = __half22float2(*(__half2*)&r.x), fb = __half22float2(*(__half2*)&r.y);
        a0.x += nv * fa.x; a0.y += nv * fa.y; a0.z += nv * fb.x; a0.w += nv * fb.y;
    }
    float4 acc = make_float4(a0.x + a1.x + a2.x + a3.x, a0.y + a1.y + a2.y + a3.y,
                             a0.z + a1.z + a2.z + a3.z, a0.w + a1.w + a2.w + a3.w);
    __half2 oa = __floats2half2_rn(acc.x, acc.y);
    __half2 ob = __floats2half2_rn(acc.z, acc.w);
    float2 o;
    *(__half2*)&o.x = oa;
    *(__half2*)&o.y = ob;
    dst16[node * TPN + c] = o;
}

// Final iteration: fp16 gather -> fp32 output
__global__ void k_pull_last(const int* __restrict__ rowptr, const int2* __restrict__ epack,
                            const float2* __restrict__ src16, const float4* __restrict__ x,
                            float4* __restrict__ out) {
    int node = blockIdx.x * NPB + threadIdx.x / TPN;
    int c = threadIdx.x % TPN;
    if (node >= N_NODES) return;
    int beg = rowptr[node], end = rowptr[node + 1];
    float4 xv = x[node * TPN + c];
    float4 a0 = make_float4(0.1f * xv.x, 0.1f * xv.y, 0.1f * xv.z, 0.1f * xv.w);
    float4 a1 = make_float4(0.f, 0.f, 0.f, 0.f);
    float4 a2 = make_float4(0.f, 0.f, 0.f, 0.f);
    float4 a3 = make_float4(0.f, 0.f, 0.f, 0.f);
    int e = beg;
    for (; e + 4 <= end; e += 4) {
        int2 p0 = epack[e], p1 = epack[e + 1], p2 = epack[e + 2], p3 = epack[e + 3];
        float2 r0 = src16[p0.x + c];
        float2 r1 = src16[p1.x + c];
        float2 r2 = src16[p2.x + c];
        float2 r3 = src16[p3.x + c];
        float n0 = __int_as_float(p0.y), n1 = __int_as_float(p1.y);
        float n2 = __int_as_float(p2.y), n3 = __int_as_float(p3.y);
        float2 f0a = __half22float2(*(__half2*)&r0.x), f0b = __half22float2(*(__half2*)&r0.y);
        float2 f1a = __half22float2(*(__half2*)&r1.x), f1b = __half22float2(*(__half2*)&r1.y);
        float2 f2a = __half22float2(*(__half2*)&r2.x), f2b = __half22float2(*(__half2*)&r2.y);
        float2 f3a = __half22float2(*(__half2*)&r3.x), f3b = __half22float2(*(__half2*)&r3.y);
        a0.x += n0 * f0a.x; a0.y += n0 * f0a.y; a0.z += n0 * f0b.x; a0.w += n0 * f0b.y;
        a1.x += n1 * f1a.x; a1.y += n1 * f1a.y; a1.z += n1 * f1b.x; a1.w += n1 * f1b.y;
        a2.x += n2 * f2a.x; a2.y += n2 * f2a.y; a2.z += n2 * f2b.x; a2.w += n2 * f2b.y;
        a3.x += n3 * f3a.x; a3.y += n3 * f3a.y; a3.z += n3 * f3b.x; a3.w += n3 * f3b.y;
    }
    for (; e < end; ++e) {
        int2 p = epack[e];
        float2 r = src16[p.x + c];
        float nv = __int_as_float(p.y);
        float2 fa = __half22float2(*(__half2*)&r.x), fb = __half22float2(*(__half2*)&r.y);
        a0.x += nv * fa.x; a0.y += nv * fa.y; a0.z += nv * fb.x; a0.w += nv * fb.y;
    }
    out[node * TPN + c] = make_float4(a0.x + a1.x + a2.x + a3.x, a0.y + a1.y + a2.y + a3.y,
                                      a0.z + a1.z + a2.z + a3.z, a0.w + a1.w + a2.w + a3.w);
}

extern "C" void kernel_launch(void* const* d_in, const int* in_sizes, int n_in,
                              void* d_out, int out_size, void* d_ws, size_t ws_size,
                              hipStream_t stream) {
    const float* x  = (const float*)d_in[0];
    const int*   ei = (const int*)d_in[1];
    const float* w  = (const float*)d_in[2];
    const int E = in_sizes[2];
    const int* row = ei;        // destination (segment id)
    const int* col = ei + E;    // message source

    // Workspace layout (all offsets 16B aligned), peak ~32.4 MB:
    //   rowptr     : int[N+1]    @ 0            (pad to 400,016)
    //   epack      : int2[E]     @ 400,016      (12,800,000) -> 13,200,016
    //   -- phase-1 temps (dead after k_fill/scan) --
    //   cnt        : int[N]      @ 13,200,016   (400,000)    -> 13,600,016
    //   pos_local  : int[E]      @ 13,600,016   (6,400,000)  -> 20,000,016
    //   thread_off : int[49*256] @ 20,000,016   (50,176)
    //   blocksum   : int[49]     @ 20,050,192
    //   blockoff   : int[49]     @ 20,050,448
    //   -- phase-2 fp16 buffers (written only after fill) --
    //   hX16       : half[N*48]  @ 13,200,016   (9,600,000)  -> 22,800,016
    //   hA16       : half[N*48]  @ 22,800,016   (9,600,000)  -> 32,400,016
    char* ws = (char*)d_ws;
    int*    rowptr     = (int*)(ws);
    int2*   epack      = (int2*)(ws + 400016);
    int*    cnt        = (int*)(ws + 13200016);
    int*    pos_local  = (int*)(ws + 13600016);
    int*    thread_off = (int*)(ws + 20000016);
    int*    blocksum   = (int*)(ws + 20050192);
    int*    blockoff   = (int*)(ws + 20050448);
    float2* hX16       = (float2*)(ws + 13200016);
    float2* hA16       = (float2*)(ws + 22800016);
    float4* out        = (float4*)d_out;

    const int B = 256;
    const int egrid = (E + B - 1) / B;

    hipMemsetAsync(cnt, 0, N_NODES * sizeof(int), stream);
    k_count<<<egrid, B, 0, stream>>>(row, cnt, pos_local, E);
    k_scanA<<<SCAN_NB, SCAN_TB, 0, stream>>>(cnt, thread_off, blocksum);
    k_scanB<<<1, 64, 0, stream>>>(blocksum, blockoff, rowptr);
    k_scanC<<<SCAN_NB, SCAN_TB, 0, stream>>>(cnt, thread_off, blockoff, rowptr);
    k_fill<<<egrid, B, 0, stream>>>(row, col, w, rowptr, pos_local, epack, E);
    k_norm<<<(N_NODES + B - 1) / B, B, 0, stream>>>(rowptr, epack);

    const int n12 = N_NODES * 12;   // float4/float2 chunk count per h buffer
    k_x2h<<<(n12 + B - 1) / B, B, 0, stream>>>((const float4*)x, hX16, n12);

    const int pgrid = (N_NODES + NPB - 1) / NPB;
    // ping-pong: X->A, A->X, ..., iter9 X->A, iter10 A->out(fp32)
    float2* src = hX16;
    float2* dst = hA16;
    for (int k = 1; k <= K_ITER - 1; ++k) {
        k_pull16<<<pgrid, NPB * TPN, 0, stream>>>(rowptr, epack, src,
                                                  (const float4*)x, dst);
        float2* t = src; src = dst; dst = t;
    }
    k_pull_last<<<pgrid, NPB * TPN, 0, stream>>>(rowptr, epack, src,
                                                 (const float4*)x, out);
}